// Round 12
// baseline (40.082 us; speedup 1.0000x reference)
//
#include <hip/hip_runtime.h>

typedef float v2f __attribute__((ext_vector_type(2)));
#define FMA2(a,b,c) __builtin_elementwise_fma((a),(b),(c))
#define MAX2(a,b)   __builtin_elementwise_max((a),(b))

#define SPOS 2500
#define SSTRIDE 2560                 // padded column count for LC rows
#define NSLICE 16
// ws layout (floats): LC float4[32][SSTRIDE] | A[64] | WoT[4096] | part[256*8*16*16]
#define WS_A_OFF    (32 * SSTRIDE * 4)
#define WS_WOT_OFF  (WS_A_OFF + 64)
#define WS_PART_OFF (WS_WOT_OFF + 4096)
#define SCL (0.35355339059327373f * 1.4426950408889634f)   // 1/sqrt(8) * log2(e)

// Kernel A: LC precompute (coalesced via LDS transpose), A[64], WoT.
// sc[h][t] = A*x^2 + L*x + C in exp2 domain; L,C shared by all 256 batches.
__global__ __launch_bounds__(256) void attn_pool_pre(
    const float* __restrict__ wq, const float* __restrict__ bq,
    const float* __restrict__ wk, const float* __restrict__ bk,
    const float* __restrict__ pe, const float* __restrict__ Wo,
    float* __restrict__ ws)
{
    const int bx  = blockIdx.x;
    const int tid = threadIdx.x;

    if (bx < 79) {
        __shared__ float4 lds[32][33];       // [j2 row][s_local], +1 pad
        const int s0 = bx * 32;
        const int sl = tid >> 3;             // s_local 0..31
        const int s  = s0 + sl;
        const int h  = tid & 7;

        if (s < SPOS) {
            float per[64];
            const float4* p4 = (const float4*)(pe + (size_t)s * 64);
            #pragma unroll
            for (int j = 0; j < 16; ++j) {
                const float4 t = p4[j];
                per[4*j] = t.x; per[4*j+1] = t.y; per[4*j+2] = t.z; per[4*j+3] = t.w;
            }

            float eq[8];
            #pragma unroll
            for (int d = 0; d < 8; ++d) eq[d] = bq[h*8+d] + per[h*8+d];

            #pragma unroll
            for (int t = 0; t < 8; t += 2) {
                float l0 = 0.f, c0 = 0.f, l1 = 0.f, c1 = 0.f;
                #pragma unroll
                for (int d = 0; d < 8; ++d) {
                    const float ek0 = bk[t*8+d]     + per[t*8+d];
                    const float ek1 = bk[(t+1)*8+d] + per[(t+1)*8+d];
                    l0 = fmaf(wq[h*8+d], ek0,   l0);
                    l0 = fmaf(wk[t*8+d], eq[d], l0);
                    c0 = fmaf(eq[d], ek0, c0);
                    l1 = fmaf(wq[h*8+d], ek1,        l1);
                    l1 = fmaf(wk[(t+1)*8+d], eq[d],  l1);
                    c1 = fmaf(eq[d], ek1, c1);
                }
                lds[h*4 + (t>>1)][sl] =
                    make_float4(l0 * SCL, l1 * SCL, c0 * SCL, c1 * SCL);
            }
        }
        __syncthreads();

        float4* lc4 = (float4*)ws;
        #pragma unroll
        for (int k = 0; k < 4; ++k) {
            const int flat = k * 256 + tid;
            const int row = flat >> 5, col = flat & 31;
            if (s0 + col < SPOS)
                lc4[(size_t)row * SSTRIDE + s0 + col] = lds[row][col];
        }
    } else if (bx == 79) {
        if (tid < 64) {
            const int hh = tid >> 3, tt = tid & 7;
            float a = 0.f;
            #pragma unroll
            for (int d = 0; d < 8; ++d) a = fmaf(wq[hh*8+d], wk[tt*8+d], a);
            ws[WS_A_OFF + tid] = a * SCL;
        }
    } else {
        const int i = (bx - 80) * 256 + tid;   // 0..4095 ; i = j*64 + f
        const int j = i >> 6, f = i & 63;
        ws[WS_WOT_OFF + i] = Wo[(size_t)f * 64 + j];   // WoT[j][f]
    }
}

// Kernel B: block = (4-batch group, slice of ~156, head-half). The block's
// whole LC working set (16 rows x <=157 float4 = 40KB) is staged into LDS in
// one burst (single latency exposure); sim values prefetched to registers
// before the barrier. Inner loop = ds_read_b128 + VALU only.
__global__ __launch_bounds__(256) void attn_pool_k1(
    const float* __restrict__ sim,
    const float* __restrict__ ws, float* __restrict__ part)
{
    __shared__ float4 lcs[16][157];        // 40192 B
    const int bx   = blockIdx.x;           // 0..2047
    const int bg   = bx >> 5;              // 0..63: batches bg*4..bg*4+3
    const int sl   = (bx >> 1) & 15;       // slice 0..15
    const int hq   = bx & 1;               // head half
    const int wave = threadIdx.x >> 6;
    const int lane = threadIdx.x & 63;
    const int h    = hq * 4 + wave;        // head 0..7

    const int s_begin = (sl * SPOS) >> 4;
    const int s_end   = ((sl + 1) * SPOS) >> 4;
    const int len     = s_end - s_begin;   // 156 or 157

    // sim prefetch: 12 values (4 batches x 3 iters), clamped addresses
    const float* simb = sim + (size_t)(bg * 4) * SPOS;
    float xv[4][3];
    #pragma unroll
    for (int nb = 0; nb < 4; ++nb)
        #pragma unroll
        for (int it = 0; it < 3; ++it) {
            int s = s_begin + it * 64 + lane;
            if (s >= s_end) s = s_begin;
            xv[nb][it] = simb[nb * SPOS + s];
        }

    // LC staging: wave w stages local rows w*4..w*4+3 (global rows hq*16+r)
    const float4* lc4 = (const float4*)ws;
    #pragma unroll
    for (int rr = 0; rr < 4; ++rr) {
        const int r = wave * 4 + rr;
        const float4* src = lc4 + (size_t)(hq * 16 + r) * SSTRIDE + s_begin;
        for (int c = lane; c < len; c += 64)
            lcs[r][c] = src[c];
    }

    // A row for this head -> 8 SGPRs
    float aA[8];
    #pragma unroll
    for (int i = 0; i < 8; ++i)
        aA[i] = __int_as_float(__builtin_amdgcn_readfirstlane(
                    __float_as_int(ws[WS_A_OFF + h * 8 + i])));

    __syncthreads();

    v2f P0[16], P1[16];   // [nb][t2]
    #pragma unroll
    for (int i = 0; i < 16; ++i) { P0[i] = (v2f)(0.f); P1[i] = (v2f)(0.f); }

    #pragma unroll 1
    for (int it = 0; it < 3; ++it) {
        const int c = it * 64 + lane;
        if (c < len) {
            float4 q[4];
            #pragma unroll
            for (int t2 = 0; t2 < 4; ++t2) q[t2] = lcs[wave*4 + t2][c];

            #pragma unroll
            for (int nb = 0; nb < 4; ++nb) {
                const float x = xv[nb][it];
                const v2f xx = {x, x};
                v2f e[4];
                #pragma unroll
                for (int t2 = 0; t2 < 4; ++t2) {
                    // Horner ((A*x + L)*x + C); first step scalar: A in SGPR
                    const float u0 = fmaf(x, aA[2*t2],   q[t2].x);
                    const float u1 = fmaf(x, aA[2*t2+1], q[t2].y);
                    const v2f uu = {u0, u1};
                    const v2f cv = {q[t2].z, q[t2].w};
                    e[t2] = FMA2(uu, xx, cv);
                }
                const v2f m2 = MAX2(MAX2(e[0], e[1]), MAX2(e[2], e[3]));
                const float m = fmaxf(m2.x, m2.y);
                const v2f ms = {m, m};
                v2f den2 = (v2f)(0.f);
                #pragma unroll
                for (int t2 = 0; t2 < 4; ++t2) {
                    v2f ee = e[t2] - ms;
                    ee.x = exp2f(ee.x); ee.y = exp2f(ee.y);
                    e[t2] = ee; den2 += ee;
                }
                const float inv  = __builtin_amdgcn_rcpf(den2.x + den2.y);
                const float xinv = x * inv;
                const v2f vi = {inv, inv}, vx = {xinv, xinv};
                #pragma unroll
                for (int t2 = 0; t2 < 4; ++t2) {
                    P0[nb*4+t2] = FMA2(vi, e[t2], P0[nb*4+t2]);
                    P1[nb*4+t2] = FMA2(vx, e[t2], P1[nb*4+t2]);
                }
            }
        }
    }

    // Flatten: av[nb*16 + t] = P0[nb][t], av[nb*16 + 8 + t] = P1[nb][t]
    float av[64];
    #pragma unroll
    for (int nb = 0; nb < 4; ++nb)
        #pragma unroll
        for (int t = 0; t < 8; ++t) {
            av[nb*16 + t]     = (t & 1) ? P0[nb*4 + (t>>1)].y : P0[nb*4 + (t>>1)].x;
            av[nb*16 + 8 + t] = (t & 1) ? P1[nb*4 + (t>>1)].y : P1[nb*4 + (t>>1)].x;
        }

    // Halving-butterfly across 64 lanes; lane ends with index bitrev6(lane).
    float r32[32];
    #pragma unroll
    for (int i = 0; i < 32; ++i) {
        const bool up = (lane & 1) != 0;
        const float keep = up ? av[i+32] : av[i];
        const float send = up ? av[i]    : av[i+32];
        r32[i] = keep + __shfl_xor(send, 1, 64);
    }
    float r16[16];
    #pragma unroll
    for (int i = 0; i < 16; ++i) {
        const bool up = (lane & 2) != 0;
        const float keep = up ? r32[i+16] : r32[i];
        const float send = up ? r32[i]    : r32[i+16];
        r16[i] = keep + __shfl_xor(send, 2, 64);
    }
    float r8[8];
    #pragma unroll
    for (int i = 0; i < 8; ++i) {
        const bool up = (lane & 4) != 0;
        const float keep = up ? r16[i+8] : r16[i];
        const float send = up ? r16[i]   : r16[i+8];
        r8[i] = keep + __shfl_xor(send, 4, 64);
    }
    float r4[4];
    #pragma unroll
    for (int i = 0; i < 4; ++i) {
        const bool up = (lane & 8) != 0;
        const float keep = up ? r8[i+4] : r8[i];
        const float send = up ? r8[i]   : r8[i+4];
        r4[i] = keep + __shfl_xor(send, 8, 64);
    }
    float r2[2];
    #pragma unroll
    for (int i = 0; i < 2; ++i) {
        const bool up = (lane & 16) != 0;
        const float keep = up ? r4[i+2] : r4[i];
        const float send = up ? r4[i]   : r4[i+2];
        r2[i] = keep + __shfl_xor(send, 16, 64);
    }
    float r1;
    {
        const bool up = (lane & 32) != 0;
        const float keep = up ? r2[1] : r2[0];
        const float send = up ? r2[0] : r2[1];
        r1 = keep + __shfl_xor(send, 32, 64);
    }

    const int f = ((lane & 1) << 5) | ((lane & 2) << 3) | ((lane & 4) << 1)
                | ((lane & 8) >> 1) | ((lane & 16) >> 3) | ((lane & 32) >> 5);
    const int nb = f >> 4, rem = f & 15;
    part[(((size_t)(bg*4 + nb) * 8 + h) * NSLICE + sl) * 16 + rem] = r1;
}

// Kernel C: 4 batches per block (one per wave): slice-sum -> wv/bv
// contraction -> mean -> @WoT (coalesced) + bo -> LayerNorm.
__global__ __launch_bounds__(256) void attn_pool_k2(
    const float* __restrict__ ws,
    const float* __restrict__ wv, const float* __restrict__ bv,
    const float* __restrict__ bo,
    const float* __restrict__ gamma, const float* __restrict__ beta,
    float* __restrict__ out)
{
    const float* part = ws + WS_PART_OFF;
    const float* WoT  = ws + WS_WOT_OFF;
    const int wave = threadIdx.x >> 6;
    const int lane = threadIdx.x & 63;
    const int b = blockIdx.x * 4 + wave;
    const int l = lane;                  // (h,t) for partials, (h,d) for pooled
    const int h = l >> 3, t = l & 7, d = t;

    float p0 = 0.f, p1 = 0.f;            // P0[h][t], P1[h][t]
    #pragma unroll
    for (int sl = 0; sl < NSLICE; ++sl) {
        const size_t base = (((size_t)b * 8 + h) * NSLICE + sl) * 16;
        p0 += part[base + t];
        p1 += part[base + 8 + t];
    }

    // pooled[h,d] = (sum_t P1[h][t]*wv[t,d] + P0[h][t]*bv[t,d]) / S
    float pool = 0.f;
    #pragma unroll
    for (int tt = 0; tt < 8; ++tt) {
        const float P1v = __shfl(p1, h*8 + tt, 64);
        const float P0v = __shfl(p0, h*8 + tt, 64);
        pool = fmaf(P1v, wv[tt*8 + d], pool);
        pool = fmaf(P0v, bv[tt*8 + d], pool);
    }
    pool *= (1.0f / 2500.0f);

    // y = bo + WoT-column dot pooled; 4 independent chains for ILP
    float y0 = 0.f, y1 = 0.f, y2 = 0.f, y3 = 0.f;
    #pragma unroll
    for (int j = 0; j < 64; j += 4) {
        const float pj0 = __shfl(pool, j + 0, 64);
        const float pj1 = __shfl(pool, j + 1, 64);
        const float pj2 = __shfl(pool, j + 2, 64);
        const float pj3 = __shfl(pool, j + 3, 64);
        y0 = fmaf(pj0, WoT[(j + 0) * 64 + l], y0);
        y1 = fmaf(pj1, WoT[(j + 1) * 64 + l], y1);
        y2 = fmaf(pj2, WoT[(j + 2) * 64 + l], y2);
        y3 = fmaf(pj3, WoT[(j + 3) * 64 + l], y3);
    }
    const float y = bo[l] + ((y0 + y1) + (y2 + y3));

    float s1 = y;
    #pragma unroll
    for (int off = 32; off > 0; off >>= 1) s1 += __shfl_xor(s1, off, 64);
    const float mu = s1 * (1.0f / 64.0f);
    const float dlt = y - mu;
    float s2 = dlt * dlt;
    #pragma unroll
    for (int off = 32; off > 0; off >>= 1) s2 += __shfl_xor(s2, off, 64);
    const float var = s2 * (1.0f / 64.0f);

    out[(size_t)b * 64 + l] = dlt * rsqrtf(var + 1e-5f) * gamma[l] + beta[l];
}

extern "C" void kernel_launch(void* const* d_in, const int* in_sizes, int n_in,
                              void* d_out, int out_size, void* d_ws, size_t ws_size,
                              hipStream_t stream) {
    const float* sim   = (const float*)d_in[0];
    const float* wq    = (const float*)d_in[1];
    const float* bq    = (const float*)d_in[2];
    const float* wk    = (const float*)d_in[3];
    const float* bk    = (const float*)d_in[4];
    const float* wv    = (const float*)d_in[5];
    const float* bv    = (const float*)d_in[6];
    const float* pe    = (const float*)d_in[7];
    const float* Wo    = (const float*)d_in[8];
    const float* bo    = (const float*)d_in[9];
    const float* gamma = (const float*)d_in[10];
    const float* beta  = (const float*)d_in[11];
    float* ws   = (float*)d_ws;                 // ~3.5 MB used
    float* part = ws + WS_PART_OFF;
    float* out  = (float*)d_out;

    attn_pool_pre<<<dim3(96),   dim3(256), 0, stream>>>(wq, bq, wk, bk, pe, Wo, ws);
    attn_pool_k1 <<<dim3(2048), dim3(256), 0, stream>>>(sim, ws, part);
    attn_pool_k2 <<<dim3(64),   dim3(256), 0, stream>>>(ws, wv, bv, bo, gamma, beta, out);
}